// Round 8
// baseline (174.819 us; speedup 1.0000x reference)
//
#include <hip/hip_runtime.h>
#include <math.h>

#define N_POS 8192
#define FEAT 512
#define NTOT (2 * N_POS)
#define BM 128
#define BN 128
#define NSTEP 16   // K-steps of 32
#define BUFB 8192  // bytes per matrix per LDS buffer (128 rows x 32 k x 2B)

#define AS1 __attribute__((address_space(1)))
#define AS3 __attribute__((address_space(3)))

typedef __attribute__((ext_vector_type(8))) short bf16x8;
typedef __attribute__((ext_vector_type(4))) short s16x4;
typedef __attribute__((ext_vector_type(4))) float f32x4;

__device__ inline unsigned long long packMax(float v, unsigned idx) {
    unsigned u = __float_as_uint(v);
    u = (u & 0x80000000u) ? ~u : (u | 0x80000000u);
    return ((unsigned long long)u << 32) | (unsigned)(~idx);
}
__device__ inline unsigned unpackIdx(unsigned long long p) {
    return ~(unsigned)(p & 0xffffffffull);
}
__device__ inline short f2bf(float f) {
    unsigned u = __float_as_uint(f);
    return (short)((u + 0x7FFFu + ((u >> 16) & 1u)) >> 16);
}

__global__ __launch_bounds__(256) void gather_convert2(
    const float* __restrict__ F0, const int* __restrict__ idx0, short* __restrict__ out0,
    const float* __restrict__ F1, const int* __restrict__ idx1, short* __restrict__ out1,
    unsigned long long* __restrict__ zbuf)
{
    if (blockIdx.x < 64) zbuf[blockIdx.x * 256 + threadIdx.x] = 0ull;
    const int per = N_POS * FEAT / 4;
    int t = blockIdx.x * 256 + threadIdx.x;
    const float* F; const int* idx; short* out;
    if (t < per) { F = F0; idx = idx0; out = out0; }
    else         { F = F1; idx = idx1; out = out1; t -= per; }
    int i  = t >> 7;
    int k4 = t & 127;
    float4 v = *(const float4*)(F + (size_t)idx[i] * FEAT + k4 * 4);
    s16x4 o = { f2bf(v.x), f2bf(v.y), f2bf(v.z), f2bf(v.w) };
    *(s16x4*)(out + (size_t)i * FEAT + k4 * 4) = o;
}

// ---- pair-row LDS layout, BK=32 (R6-verified, 0 bank conflicts) ----
// LDS line l (128 B) holds rows {2l, 2l+1}: packed slot p = (r&1)*4 + kchunk,
// stored at slot s = p ^ (l&7).
__device__ inline bf16x8 fragP(const short* S, int row, int kh) {
    int line = row >> 1;
    int slot = (((row & 1) << 2) | kh) ^ (line & 7);
    return *(const bf16x8*)((const char*)S + line * 128 + slot * 16);
}

#define VMCNT(n)  asm volatile("s_waitcnt vmcnt(" #n ")" ::: "memory")
#define BARRAW    asm volatile("s_barrier" ::: "memory")

__global__ __launch_bounds__(256, 4) void gemm_bf16_argmax(
    const short* __restrict__ Abf, const short* __restrict__ Bbf,
    unsigned long long* __restrict__ row_best,
    unsigned long long* __restrict__ col_best)
{
    __shared__ __align__(16) short As[3][4096];        // 3 x 8 KB
    __shared__ __align__(16) short Bs[3][4096];        // 3 x 8 KB
    __shared__ unsigned long long redR[BM], redC[BN];  // 2 KB -> 50 KB, 3 blk/CU

    const int tid  = threadIdx.x;
    const int lane = tid & 63;
    const int w    = tid >> 6;          // 4 waves
    const int wm   = w >> 1, wn = w & 1;
    const int l15  = lane & 15, kh = lane >> 4;

    // 2-level XCD swizzle (R4-verified FETCH reduction)
    const int bid  = blockIdx.x;
    const int xcd  = bid & 7;
    const int loc  = bid >> 3;
    const int cg   = loc >> 5;
    const int r8   = (loc & 31) >> 2;
    const int c4   = loc & 3;
    const int brow = (xcd * 8 + r8) * BM;
    const int bcol = (cg * 4 + c4) * BN;

    if (tid < BM) redR[tid] = 0ull; else redC[tid - BM] = 0ull;

    // staging decode (pair-row inverse permutation), constant per lane
    const int iLoc   = lane >> 3;
    const int p      = (lane & 7) ^ iLoc;
    const int rowOff = iLoc * 2 + (p >> 2);
    const int colOff = (p & 3) * 8;

    // wave w stages rows w*32..w*32+31 of A and B; 4 gload_lds per wave per stage
#define STAGE(off, t)                                                                      \
    {                                                                                      \
        _Pragma("unroll")                                                                  \
        for (int u = 0; u < 2; ++u) {                                                      \
            __builtin_amdgcn_global_load_lds(                                              \
                (const AS1 unsigned int*)(Abf +                                            \
                    (size_t)(brow + w * 32 + u * 16 + rowOff) * FEAT + (t) * 32 + colOff), \
                (AS3 unsigned int*)((char*)&As[0][0] + (off) + w * 2048 + u * 1024 + lane * 16), \
                16, 0, 0);                                                                 \
            __builtin_amdgcn_global_load_lds(                                              \
                (const AS1 unsigned int*)(Bbf +                                            \
                    (size_t)(bcol + w * 32 + u * 16 + rowOff) * FEAT + (t) * 32 + colOff), \
                (AS3 unsigned int*)((char*)&Bs[0][0] + (off) + w * 2048 + u * 1024 + lane * 16), \
                16, 0, 0);                                                                 \
        }                                                                                  \
    }

    f32x4 acc[4][4];
    #pragma unroll
    for (int m = 0; m < 4; ++m)
        #pragma unroll
        for (int n = 0; n < 4; ++n)
            acc[m][n] = (f32x4)0.f;

    // ---- prologue: stage t0->buf0, t1->buf1; wait only for t0 ----
    STAGE(0, 0);
    STAGE(BUFB, 1);
    VMCNT(4);          // 8 in flight -> 4: stage(0) complete
    BARRAW;

    int curOff = 0;            // buf holding tile t
    int nxtOff = 2 * BUFB;     // buf for tile t+2
    for (int t = 0; t < NSTEP; ++t) {
        if (t + 2 < NSTEP) STAGE(nxtOff, t + 2);   // issue 2 steps ahead

        const short* Sa = (const short*)((const char*)&As[0][0] + curOff);
        const short* Sb = (const short*)((const char*)&Bs[0][0] + curOff);
        bf16x8 a[4], b[4];
        #pragma unroll
        for (int i = 0; i < 4; ++i) {
            a[i] = fragP(Sa, wm * 64 + i * 16 + l15, kh);
            b[i] = fragP(Sb, wn * 64 + i * 16 + l15, kh);
        }
        __builtin_amdgcn_s_setprio(1);
        #pragma unroll
        for (int m = 0; m < 4; ++m)
            #pragma unroll
            for (int n = 0; n < 4; ++n)
                acc[m][n] = __builtin_amdgcn_mfma_f32_16x16x32_bf16(a[m], b[n], acc[m][n], 0, 0, 0);
        __builtin_amdgcn_s_setprio(0);

        // counted drain: only require stage(t+1) landed (issued a full step ago)
        if (t + 2 < NSTEP)      { VMCNT(4); }   // stage(t+2) may stay in flight
        else if (t + 1 < NSTEP) { VMCNT(0); }   // t=14: drain stage(15)
        BARRAW;

        curOff = (curOff == 2 * BUFB) ? 0 : curOff + BUFB;
        nxtOff = (nxtOff == 2 * BUFB) ? 0 : nxtOff + BUFB;
    }
#undef STAGE

    // ---- fused argmax epilogue (verified mapping) ----
    // lane holds C[row = wm*64 + m*16 + kh*4 + j][col = wn*64 + n*16 + l15]
    #pragma unroll
    for (int m = 0; m < 4; ++m) {
        #pragma unroll
        for (int j = 0; j < 4; ++j) {
            float best = acc[m][0][j]; int bn_ = 0;
            #pragma unroll
            for (int n = 1; n < 4; ++n)
                if (acc[m][n][j] > best) { best = acc[m][n][j]; bn_ = n; }
            unsigned long long pk = packMax(best, (unsigned)(bcol + wn * 64 + bn_ * 16 + l15));
            #pragma unroll
            for (int mask = 1; mask <= 8; mask <<= 1) {
                unsigned long long q = __shfl_xor(pk, mask);
                if (q > pk) pk = q;
            }
            if (l15 == 0)
                atomicMax(&redR[wm * 64 + m * 16 + kh * 4 + j], pk);
        }
    }
    #pragma unroll
    for (int n = 0; n < 4; ++n) {
        float best = acc[0][n][0]; int bm_ = 0, bj_ = 0;
        #pragma unroll
        for (int m = 0; m < 4; ++m)
            #pragma unroll
            for (int j = 0; j < 4; ++j)
                if (acc[m][n][j] > best) { best = acc[m][n][j]; bm_ = m; bj_ = j; }
        unsigned long long pk = packMax(best, (unsigned)(brow + wm * 64 + bm_ * 16 + kh * 4 + bj_));
        #pragma unroll
        for (int mask = 16; mask <= 32; mask <<= 1) {
            unsigned long long q = __shfl_xor(pk, mask);
            if (q > pk) pk = q;
        }
        if (kh == 0)
            atomicMax(&redC[wn * 64 + n * 16 + l15], pk);
    }
    __syncthreads();
    if (tid < BM) atomicMax(&row_best[brow + tid], redR[tid]);
    else          atomicMax(&col_best[bcol + tid - BM], redC[tid - BM]);
}

__global__ __launch_bounds__(1024) void finalize_loss(
    const float* __restrict__ T4,
    const float* __restrict__ src_points, const float* __restrict__ tgt_points,
    const float* __restrict__ src_scores, const float* __restrict__ tgt_scores,
    const int* __restrict__ sidx, const int* __restrict__ tidx,
    const unsigned long long* __restrict__ row_best,
    const unsigned long long* __restrict__ col_best,
    float* __restrict__ out)
{
    const int tid = threadIdx.x;
    const float R00=T4[0],R01=T4[1],R02=T4[2],t0=T4[3];
    const float R10=T4[4],R11=T4[5],R12=T4[6],t1=T4[7];
    const float R20=T4[8],R21=T4[9],R22=T4[10],t2=T4[11];

    unsigned nn[16];
    #pragma unroll
    for (int u = 0; u < 16; ++u) {
        int i = tid + u * 1024;
        nn[u] = unpackIdx(i < N_POS ? row_best[i] : col_best[i - N_POS]);
    }
    int sI[16], tI[16];
    #pragma unroll
    for (int u = 0; u < 16; ++u) {
        int i = tid + u * 1024;
        if (i < N_POS) { sI[u] = sidx[i];     tI[u] = tidx[nn[u]]; }
        else           { sI[u] = sidx[nn[u]]; tI[u] = tidx[i - N_POS]; }
    }
    float sc[16];
    #pragma unroll
    for (int u = 0; u < 16; ++u) {
        int i = tid + u * 1024;
        sc[u] = (i < N_POS) ? src_scores[sI[u]] : tgt_scores[tI[u]];
    }
    float spx[16], spy[16], spz[16], tpx[16], tpy[16], tpz[16];
    #pragma unroll
    for (int u = 0; u < 16; ++u) {
        const float* p = src_points + (size_t)sI[u] * 3;
        spx[u] = p[0]; spy[u] = p[1]; spz[u] = p[2];
        const float* q = tgt_points + (size_t)tI[u] * 3;
        tpx[u] = q[0]; tpy[u] = q[1]; tpz[u] = q[2];
    }

    double S1 = 0.0, S0 = 0.0;
    float cnt = 0.f, sumres = 0.f, corr = 0.f;
    #pragma unroll
    for (int u = 0; u < 16; ++u) {
        float px = R00*spx[u]+R01*spy[u]+R02*spz[u]+t0;
        float py = R10*spx[u]+R11*spy[u]+R12*spz[u]+t1;
        float pz = R20*spx[u]+R21*spy[u]+R22*spz[u]+t2;
        float dx = px-tpx[u], dy = py-tpy[u], dz = pz-tpz[u];
        float label = (sqrtf(dx*dx+dy*dy+dz*dz) < 0.1f) ? 1.f : 0.f;
        cnt += label;
        float res = (sc[u] > 0.5f) ? 1.f : 0.f;
        sumres += res;
        corr += res * label;
        if (label > 0.5f) S1 += (double)(-logf(sc[u]));
        else              S0 += (double)(-logf(1.0f - sc[u]));
    }

    #pragma unroll
    for (int off = 32; off > 0; off >>= 1) {
        S1 += __shfl_down(S1, off);
        S0 += __shfl_down(S0, off);
        cnt += __shfl_down(cnt, off);
        sumres += __shfl_down(sumres, off);
        corr += __shfl_down(corr, off);
    }
    __shared__ double sh1[16], sh0[16];
    __shared__ float shc[16], shr[16], shco[16];
    int wid = tid >> 6, lane = tid & 63;
    if (lane == 0) { sh1[wid]=S1; sh0[wid]=S0; shc[wid]=cnt; shr[wid]=sumres; shco[wid]=corr; }
    __syncthreads();
    if (tid == 0) {
        double s1 = 0, s0 = 0; float c = 0, rr = 0, co = 0;
        for (int v = 0; v < 16; ++v) { s1+=sh1[v]; s0+=sh0[v]; c+=shc[v]; rr+=shr[v]; co+=shco[v]; }
        float nw = c / (float)NTOT;
        float loss = (float)((nw * s1 + (1.0 - (double)nw) * s0) / (double)NTOT);
        out[0] = loss;
        out[1] = co / (rr + 1e-12f);
        out[2] = co / (c + 1e-12f);
    }
}

extern "C" void kernel_launch(void* const* d_in, const int* in_sizes, int n_in,
                              void* d_out, int out_size, void* d_ws, size_t ws_size,
                              hipStream_t stream) {
    const float* T4         = (const float*)d_in[0];
    const float* src_points = (const float*)d_in[1];
    const float* tgt_points = (const float*)d_in[2];
    const float* src_scores = (const float*)d_in[3];
    const float* tgt_scores = (const float*)d_in[4];
    const float* src_feats  = (const float*)d_in[5];
    const float* tgt_feats  = (const float*)d_in[6];
    const int*   sidx       = (const int*)d_in[7];
    const int*   tidx       = (const int*)d_in[8];

    unsigned long long* row_best = (unsigned long long*)d_ws;
    unsigned long long* col_best = row_best + N_POS;
    short* Abf = (short*)((char*)d_ws + 2 * N_POS * sizeof(unsigned long long));
    short* Bbf = Abf + (size_t)N_POS * FEAT;
    float* out = (float*)d_out;

    hipLaunchKernelGGL(gather_convert2, dim3(2 * N_POS * FEAT / 4 / 256), dim3(256), 0, stream,
                       src_feats, sidx, Abf, tgt_feats, tidx, Bbf, row_best);
    hipLaunchKernelGGL(gemm_bf16_argmax, dim3((N_POS / BM) * (N_POS / BN)), dim3(256), 0, stream,
                       Abf, Bbf, row_best, col_best);
    hipLaunchKernelGGL(finalize_loss, dim3(1), dim3(1024), 0, stream,
                       T4, src_points, tgt_points, src_scores, tgt_scores,
                       sidx, tidx, row_best, col_best, out);
}

// Round 9
// 159.131 us; speedup vs baseline: 1.0986x; 1.0986x over previous
//
#include <hip/hip_runtime.h>
#include <math.h>

#define N_POS 8192
#define FEAT 512
#define NTOT (2 * N_POS)
#define BM 128
#define BN 128

typedef __attribute__((ext_vector_type(8))) short bf16x8;
typedef __attribute__((ext_vector_type(4))) short s16x4;
typedef __attribute__((ext_vector_type(4))) float f32x4;

__device__ inline unsigned long long packMax(float v, unsigned idx) {
    unsigned u = __float_as_uint(v);
    u = (u & 0x80000000u) ? ~u : (u | 0x80000000u);
    return ((unsigned long long)u << 32) | (unsigned)(~idx);
}
__device__ inline unsigned unpackIdx(unsigned long long p) {
    return ~(unsigned)(p & 0xffffffffull);
}
__device__ inline short f2bf(float f) {
    unsigned u = __float_as_uint(f);
    return (short)((u + 0x7FFFu + ((u >> 16) & 1u)) >> 16);
}

// gather + convert into FRAGMENT-MAJOR layout:
// slot index t = ((r16*16 + k32)*64 + kh*16 + l15), 16 B per slot,
// holds X[r16*16 + l15][k32*32 + kh*8 .. +7] as bf16.
// A wave's MFMA fragment load (16 rows x one 8-k chunk per lane quartet) is
// then ONE contiguous 1024-B global_load_dwordx4.
__global__ __launch_bounds__(256) void gather_convert2(
    const float* __restrict__ F0, const int* __restrict__ idx0, short* __restrict__ out0,
    const float* __restrict__ F1, const int* __restrict__ idx1, short* __restrict__ out1,
    unsigned long long* __restrict__ zbuf)
{
    if (blockIdx.x < 64) zbuf[blockIdx.x * 256 + threadIdx.x] = 0ull;
    const int per = N_POS * FEAT / 8;          // 16-B slots per matrix
    int t = blockIdx.x * 256 + threadIdx.x;
    const float* F; const int* idx; short* out;
    if (t < per) { F = F0; idx = idx0; out = out0; }
    else         { F = F1; idx = idx1; out = out1; t -= per; }
    int l15 = t & 15, kh = (t >> 4) & 3, k32 = (t >> 6) & 15, r16 = t >> 10;
    int row = r16 * 16 + l15;
    const float* src = F + (size_t)idx[row] * FEAT + k32 * 32 + kh * 8;
    float4 v0 = *(const float4*)src;
    float4 v1 = *(const float4*)(src + 4);
    s16x4 o0 = { f2bf(v0.x), f2bf(v0.y), f2bf(v0.z), f2bf(v0.w) };
    s16x4 o1 = { f2bf(v1.x), f2bf(v1.y), f2bf(v1.z), f2bf(v1.w) };
    *(s16x4*)(out + (size_t)t * 8)     = o0;
    *(s16x4*)(out + (size_t)t * 8 + 4) = o1;
}

// LDS-free streaming GEMM: fragments straight from L2, register double-buffer,
// no barriers in the K-loop.
__global__ __launch_bounds__(256, 3) void gemm_bf16_argmax(
    const short* __restrict__ Abf, const short* __restrict__ Bbf,
    unsigned long long* __restrict__ row_best,
    unsigned long long* __restrict__ col_best)
{
    __shared__ unsigned long long redR[BM], redC[BN];   // 2 KB only

    const int tid  = threadIdx.x;
    const int lane = tid & 63;
    const int w    = tid >> 6;          // 4 waves
    const int wm   = w >> 1, wn = w & 1;
    const int l15  = lane & 15, kh = lane >> 4;

    // 2-level XCD swizzle (R4-verified)
    const int bid  = blockIdx.x;
    const int xcd  = bid & 7;
    const int loc  = bid >> 3;
    const int cg   = loc >> 5;
    const int r8   = (loc & 31) >> 2;
    const int c4   = loc & 3;
    const int brow = (xcd * 8 + r8) * BM;
    const int bcol = (cg * 4 + c4) * BN;

    if (tid < BM) redR[tid] = 0ull; else redC[tid - BM] = 0ull;

    // per-fragment stream pointers (k32 = 0), advance 1024 B per K-step
    const char* aP[4];
    const char* bP[4];
    #pragma unroll
    for (int i = 0; i < 4; ++i) {
        aP[i] = (const char*)Abf + (size_t)(brow / 16 + wm * 4 + i) * 16384 + lane * 16;
        bP[i] = (const char*)Bbf + (size_t)(bcol / 16 + wn * 4 + i) * 16384 + lane * 16;
    }

    f32x4 acc[4][4];
    #pragma unroll
    for (int m = 0; m < 4; ++m)
        #pragma unroll
        for (int n = 0; n < 4; ++n)
            acc[m][n] = (f32x4)0.f;

    bf16x8 a0[4], b0[4], a1[4], b1[4];

#define LOADF(AR, BR)                                                    \
    {                                                                    \
        _Pragma("unroll")                                                \
        for (int i = 0; i < 4; ++i) {                                    \
            AR[i] = *(const bf16x8*)aP[i];  aP[i] += 1024;               \
            BR[i] = *(const bf16x8*)bP[i];  bP[i] += 1024;               \
        }                                                                \
    }
#define MFMAS(AR, BR)                                                    \
    {                                                                    \
        _Pragma("unroll")                                                \
        for (int m = 0; m < 4; ++m)                                      \
            _Pragma("unroll")                                            \
            for (int n = 0; n < 4; ++n)                                  \
                acc[m][n] = __builtin_amdgcn_mfma_f32_16x16x32_bf16(     \
                    AR[m], BR[n], acc[m][n], 0, 0, 0);                   \
    }

    LOADF(a0, b0);      // k-step 0
    LOADF(a1, b1);      // k-step 1

    #pragma unroll
    for (int it = 0; it < 8; ++it) {
        MFMAS(a0, b0);                      // consume step 2*it
        if (it < 7) LOADF(a0, b0);          // prefetch step 2*it+2
        MFMAS(a1, b1);                      // consume step 2*it+1
        if (it < 7) LOADF(a1, b1);          // prefetch step 2*it+3
    }
#undef LOADF
#undef MFMAS

    __syncthreads();   // redR/redC inits visible before epilogue atomics

    // ---- fused argmax epilogue (verified mapping) ----
    // lane holds C[row = wm*64 + m*16 + kh*4 + j][col = wn*64 + n*16 + l15]
    #pragma unroll
    for (int m = 0; m < 4; ++m) {
        #pragma unroll
        for (int j = 0; j < 4; ++j) {
            float best = acc[m][0][j]; int bn_ = 0;
            #pragma unroll
            for (int n = 1; n < 4; ++n)
                if (acc[m][n][j] > best) { best = acc[m][n][j]; bn_ = n; }
            unsigned long long pk = packMax(best, (unsigned)(bcol + wn * 64 + bn_ * 16 + l15));
            #pragma unroll
            for (int mask = 1; mask <= 8; mask <<= 1) {
                unsigned long long q = __shfl_xor(pk, mask);
                if (q > pk) pk = q;
            }
            if (l15 == 0)
                atomicMax(&redR[wm * 64 + m * 16 + kh * 4 + j], pk);
        }
    }
    #pragma unroll
    for (int n = 0; n < 4; ++n) {
        float best = acc[0][n][0]; int bm_ = 0, bj_ = 0;
        #pragma unroll
        for (int m = 0; m < 4; ++m)
            #pragma unroll
            for (int j = 0; j < 4; ++j)
                if (acc[m][n][j] > best) { best = acc[m][n][j]; bm_ = m; bj_ = j; }
        unsigned long long pk = packMax(best, (unsigned)(brow + wm * 64 + bm_ * 16 + kh * 4 + bj_));
        #pragma unroll
        for (int mask = 16; mask <= 32; mask <<= 1) {
            unsigned long long q = __shfl_xor(pk, mask);
            if (q > pk) pk = q;
        }
        if (kh == 0)
            atomicMax(&redC[wn * 64 + n * 16 + l15], pk);
    }
    __syncthreads();
    if (tid < BM) atomicMax(&row_best[brow + tid], redR[tid]);
    else          atomicMax(&col_best[bcol + tid - BM], redC[tid - BM]);
}

__global__ __launch_bounds__(1024) void finalize_loss(
    const float* __restrict__ T4,
    const float* __restrict__ src_points, const float* __restrict__ tgt_points,
    const float* __restrict__ src_scores, const float* __restrict__ tgt_scores,
    const int* __restrict__ sidx, const int* __restrict__ tidx,
    const unsigned long long* __restrict__ row_best,
    const unsigned long long* __restrict__ col_best,
    float* __restrict__ out)
{
    const int tid = threadIdx.x;
    const float R00=T4[0],R01=T4[1],R02=T4[2],t0=T4[3];
    const float R10=T4[4],R11=T4[5],R12=T4[6],t1=T4[7];
    const float R20=T4[8],R21=T4[9],R22=T4[10],t2=T4[11];

    unsigned nn[16];
    #pragma unroll
    for (int u = 0; u < 16; ++u) {
        int i = tid + u * 1024;
        nn[u] = unpackIdx(i < N_POS ? row_best[i] : col_best[i - N_POS]);
    }
    int sI[16], tI[16];
    #pragma unroll
    for (int u = 0; u < 16; ++u) {
        int i = tid + u * 1024;
        if (i < N_POS) { sI[u] = sidx[i];     tI[u] = tidx[nn[u]]; }
        else           { sI[u] = sidx[nn[u]]; tI[u] = tidx[i - N_POS]; }
    }
    float sc[16];
    #pragma unroll
    for (int u = 0; u < 16; ++u) {
        int i = tid + u * 1024;
        sc[u] = (i < N_POS) ? src_scores[sI[u]] : tgt_scores[tI[u]];
    }
    float spx[16], spy[16], spz[16], tpx[16], tpy[16], tpz[16];
    #pragma unroll
    for (int u = 0; u < 16; ++u) {
        const float* p = src_points + (size_t)sI[u] * 3;
        spx[u] = p[0]; spy[u] = p[1]; spz[u] = p[2];
        const float* q = tgt_points + (size_t)tI[u] * 3;
        tpx[u] = q[0]; tpy[u] = q[1]; tpz[u] = q[2];
    }

    double S1 = 0.0, S0 = 0.0;
    float cnt = 0.f, sumres = 0.f, corr = 0.f;
    #pragma unroll
    for (int u = 0; u < 16; ++u) {
        float px = R00*spx[u]+R01*spy[u]+R02*spz[u]+t0;
        float py = R10*spx[u]+R11*spy[u]+R12*spz[u]+t1;
        float pz = R20*spx[u]+R21*spy[u]+R22*spz[u]+t2;
        float dx = px-tpx[u], dy = py-tpy[u], dz = pz-tpz[u];
        float label = (sqrtf(dx*dx+dy*dy+dz*dz) < 0.1f) ? 1.f : 0.f;
        cnt += label;
        float res = (sc[u] > 0.5f) ? 1.f : 0.f;
        sumres += res;
        corr += res * label;
        if (label > 0.5f) S1 += (double)(-logf(sc[u]));
        else              S0 += (double)(-logf(1.0f - sc[u]));
    }

    #pragma unroll
    for (int off = 32; off > 0; off >>= 1) {
        S1 += __shfl_down(S1, off);
        S0 += __shfl_down(S0, off);
        cnt += __shfl_down(cnt, off);
        sumres += __shfl_down(sumres, off);
        corr += __shfl_down(corr, off);
    }
    __shared__ double sh1[16], sh0[16];
    __shared__ float shc[16], shr[16], shco[16];
    int wid = tid >> 6, lane = tid & 63;
    if (lane == 0) { sh1[wid]=S1; sh0[wid]=S0; shc[wid]=cnt; shr[wid]=sumres; shco[wid]=corr; }
    __syncthreads();
    if (tid == 0) {
        double s1 = 0, s0 = 0; float c = 0, rr = 0, co = 0;
        for (int v = 0; v < 16; ++v) { s1+=sh1[v]; s0+=sh0[v]; c+=shc[v]; rr+=shr[v]; co+=shco[v]; }
        float nw = c / (float)NTOT;
        float loss = (float)((nw * s1 + (1.0 - (double)nw) * s0) / (double)NTOT);
        out[0] = loss;
        out[1] = co / (rr + 1e-12f);
        out[2] = co / (c + 1e-12f);
    }
}

extern "C" void kernel_launch(void* const* d_in, const int* in_sizes, int n_in,
                              void* d_out, int out_size, void* d_ws, size_t ws_size,
                              hipStream_t stream) {
    const float* T4         = (const float*)d_in[0];
    const float* src_points = (const float*)d_in[1];
    const float* tgt_points = (const float*)d_in[2];
    const float* src_scores = (const float*)d_in[3];
    const float* tgt_scores = (const float*)d_in[4];
    const float* src_feats  = (const float*)d_in[5];
    const float* tgt_feats  = (const float*)d_in[6];
    const int*   sidx       = (const int*)d_in[7];
    const int*   tidx       = (const int*)d_in[8];

    unsigned long long* row_best = (unsigned long long*)d_ws;
    unsigned long long* col_best = row_best + N_POS;
    short* Abf = (short*)((char*)d_ws + 2 * N_POS * sizeof(unsigned long long));
    short* Bbf = Abf + (size_t)N_POS * FEAT;
    float* out = (float*)d_out;

    hipLaunchKernelGGL(gather_convert2, dim3(2 * N_POS * FEAT / 8 / 256), dim3(256), 0, stream,
                       src_feats, sidx, Abf, tgt_feats, tidx, Bbf, row_best);
    hipLaunchKernelGGL(gemm_bf16_argmax, dim3((N_POS / BM) * (N_POS / BN)), dim3(256), 0, stream,
                       Abf, Bbf, row_best, col_best);
    hipLaunchKernelGGL(finalize_loss, dim3(1), dim3(1024), 0, stream,
                       T4, src_points, tgt_points, src_scores, tgt_scores,
                       sidx, tidx, row_best, col_best, out);
}